// Round 9
// baseline (1017.116 us; speedup 1.0000x reference)
//
#include <hip/hip_runtime.h>
#include <hip/hip_bf16.h>
#include <stdint.h>

// QuantizedLinear: Y[M][N] = scale * (X[M][K] @ W[N][K]^T) + bias[N]
// M=8192, K=4096, N=16384. X fp32, W int32 (harness widens int8), out fp32.
// Round 9: register-prefetch pipeline. In epoch E: issue STAGEs, issue
// ds_reads for epoch E+1's fragments (region confirmed end of E-1 via
// WAIT4), then run epoch E's MFMAs on fragments read during E-1. MFMA's
// lgkmcnt waits on ALREADY-COMPLETE reads; the 12 new reads drain under
// the MFMA block -> LDS pipe overlaps matrix pipe. WAIT8->WAIT4 tightens
// stage confirmation by one epoch to enable the prefetch. Ring re-derived:
// stage issue at u-3, confirm end of u-2, prefetch at u-1, MFMA at u;
// region rewrite >= 2 barriers after last read. Tail: WAIT0 at epoch
// 2*NT-3; last two epochs need no wait/barrier.

typedef __attribute__((ext_vector_type(4))) float f32x4;
typedef __attribute__((ext_vector_type(4))) int i32x4;
typedef __attribute__((ext_vector_type(8))) short bf16x8s;
typedef __attribute__((ext_vector_type(4))) unsigned int u32x4;

__device__ __forceinline__ uint32_t f2bf_rne(float f) {
  uint32_t x = __float_as_uint(f);
  return (x + 0x7FFFu + ((x >> 16) & 1u)) >> 16;
}
__device__ __forceinline__ uint32_t pk2_rne(float lo, float hi) {
  return f2bf_rne(lo) | (f2bf_rne(hi) << 16);
}
__device__ __forceinline__ uint32_t pk2_trunc(float lo, float hi) {
  return (__float_as_uint(lo) >> 16) | (__float_as_uint(hi) & 0xFFFF0000u);
}

#define GLOAD_LDS16(g, l)                                        \
  __builtin_amdgcn_global_load_lds(                              \
      (const __attribute__((address_space(1))) void*)(g),        \
      (__attribute__((address_space(3))) void*)(l), 16, 0, 0)

// ---------------- conversion kernels (NT loads: inputs are read-once) ------
__global__ __launch_bounds__(256) void conv_x_kernel(
    const float* __restrict__ x, uint16_t* __restrict__ out, int n8) {
  const int stride = blockDim.x * gridDim.x;
  for (int i = blockIdx.x * blockDim.x + threadIdx.x; i < n8; i += stride) {
    f32x4 v0 = __builtin_nontemporal_load((const f32x4*)x + i * 2);
    f32x4 v1 = __builtin_nontemporal_load((const f32x4*)x + i * 2 + 1);
    u32x4 o;
    o.x = pk2_rne(v0.x, v0.y);
    o.y = pk2_rne(v0.z, v0.w);
    o.z = pk2_rne(v1.x, v1.y);
    o.w = pk2_rne(v1.z, v1.w);
    ((u32x4*)out)[i] = o;
  }
}

__global__ __launch_bounds__(256) void conv_w_kernel(
    const int32_t* __restrict__ w, uint16_t* __restrict__ out, int n8) {
  const int stride = blockDim.x * gridDim.x;
  for (int i = blockIdx.x * blockDim.x + threadIdx.x; i < n8; i += stride) {
    i32x4 v0 = __builtin_nontemporal_load((const i32x4*)w + i * 2);
    i32x4 v1 = __builtin_nontemporal_load((const i32x4*)w + i * 2 + 1);
    u32x4 o;
    o.x = pk2_trunc((float)v0.x, (float)v0.y);
    o.y = pk2_trunc((float)v0.z, (float)v0.w);
    o.z = pk2_trunc((float)v1.x, (float)v1.y);
    o.w = pk2_trunc((float)v1.z, (float)v1.w);
    ((u32x4*)out)[i] = o;
  }
}

// ---------------- 256x256 GEMM, register-prefetch pipeline ----------------
// LDS layout (dynamic, 131072 B): buf b at b*65536; A at +0, B at +32768;
// within A/B: K-half block kk at kk*16384 = [256 rows][32 bf16] (64 B rows).
// Swizzle: physical 16B-chunk = logical_chunk ^ ((row>>1)&3)  (involution).
// Staged via pre-swizzled GLOBAL source + linear LDS dest (rule #21).

#define BARRIER() __builtin_amdgcn_s_barrier()

#define WAIT4 asm volatile("s_waitcnt vmcnt(4)" ::: "memory"); __builtin_amdgcn_sched_barrier(0)
#define WAIT0 asm volatile("s_waitcnt vmcnt(0)" ::: "memory"); __builtin_amdgcn_sched_barrier(0)

#define STAGE(mat_base, koffb, ldsbase)                                      \
  {                                                                          \
    GLOAD_LDS16((mat_base) + (size_t)srow * RSB + (koffb) + skch,            \
                (ldsbase) + tid * 16);                                       \
    GLOAD_LDS16((mat_base) + (size_t)(srow + 128) * RSB + (koffb) + skch,    \
                (ldsbase) + 8192 + tid * 16);                                \
  }

#define ABLK(buf, kk) ((buf) + (kk) * 16384)
#define BBLK(buf, kk) ((buf) + 32768 + (kk) * 16384)

#define READ_A(dst, base)                                                    \
  _Pragma("unroll") for (int j = 0; j < 8; ++j) {                            \
    const int r_ = wm * 128 + j * 16 + r16;                                  \
    dst[j] = *(const bf16x8s*)((base) + r_ * 64 + chb);                      \
  }

#define READ_B(dst, base)                                                    \
  _Pragma("unroll") for (int ni = 0; ni < 4; ++ni) {                         \
    const int r_ = wn * 64 + ni * 16 + r16;                                  \
    dst[ni] = *(const bf16x8s*)((base) + r_ * 64 + chb);                     \
  }

// MFMAs on a full epoch's fragments (8 A-frags x 4 B-frags = 32 MFMAs).
#define MFMA32(av, bv)                                                       \
  __builtin_amdgcn_s_setprio(1);                                             \
  _Pragma("unroll") for (int j = 0; j < 8; ++j)                              \
    _Pragma("unroll") for (int ni = 0; ni < 4; ++ni)                         \
      acc[j][ni] = __builtin_amdgcn_mfma_f32_16x16x32_bf16(                  \
          av[j], bv[ni], acc[j][ni], 0, 0, 0);                               \
  __builtin_amdgcn_s_setprio(0);

#define PIN() __builtin_amdgcn_sched_barrier(0)

__global__ __launch_bounds__(512, 2) void qlinear_gemm_256_kernel(
    const uint16_t* __restrict__ Xb,  // [M][K] bf16
    const uint16_t* __restrict__ Wb,  // [N][K] bf16
    const float* __restrict__ scalep,
    const float* __restrict__ bias,
    float* __restrict__ Y)
{
  constexpr int N = 16384, K = 4096;
  constexpr int RSB = K * 2;   // panel row stride, bytes
  constexpr int NT = K / 64;   // 64 K-tiles

  extern __shared__ __align__(16) char lds[];  // 131072 B

  const int tid  = threadIdx.x;
  const int lane = tid & 63;
  const int wid  = tid >> 6;   // 0..7
  const int wm   = wid >> 2;   // 0..1  (M-half of block)
  const int wn   = wid & 3;    // 0..3  (N-quarter of block)
  const int r16  = lane & 15;
  const int g4   = lane >> 4;  // logical k-chunk 0..3
  const int chb  = (g4 ^ ((r16 >> 1) & 3)) << 4;  // swizzled chunk byte off

  const int srow = tid >> 2;                              // 0..127
  const int skch = ((tid & 3) ^ ((tid >> 3) & 3)) * 16;   // pre-swizzled src

  // ---- 2D super-tile mapping: grid 2048 = 32 bm x 64 bn ----
  // XCD k (= bid&7) owns one 16x16 patch; working set 192MB stays in L3.
  const int bid = blockIdx.x;
  const int xcd = bid & 7;
  const int l   = bid >> 3;          // 0..255
  const int bm  = (xcd & 1) * 16 + (l >> 4);
  const int bn  = (xcd >> 1) * 16 + (l & 15);

  f32x4 acc[8][4];
#pragma unroll
  for (int i = 0; i < 8; ++i)
#pragma unroll
    for (int j = 0; j < 4; ++j) acc[i][j] = (f32x4)0.f;

  // Two named fragment sets (P for even epochs, Q for odd) — static
  // indexing only (rule #20).
  bf16x8s pa[8], pb[4], qa[8], qb[4];

  const char* Xp = (const char*)Xb + (size_t)(bm * 256) * RSB;
  const char* Wp = (const char*)Wb + (size_t)(bn * 256) * RSB;

  // ---- prologue: stage (0,k0),(0,k1),(1,k0); confirm first two; read P ----
  STAGE(Xp, 0,   ABLK(lds, 0));
  STAGE(Wp, 0,   BBLK(lds, 0));
  STAGE(Xp, 64,  ABLK(lds, 1));
  STAGE(Wp, 64,  BBLK(lds, 1));
  STAGE(Xp, 128, ABLK(lds + 65536, 0));
  STAGE(Wp, 128, BBLK(lds + 65536, 0));
  WAIT4;        // 12 -> 4 outstanding: confirms (0,k0) and (0,k1)
  BARRIER();
  READ_A(pa, ABLK(lds, 0));
  READ_B(pb, BBLK(lds, 0));

  // ---- main loop: tiles 0 .. NT-3 ----
  for (int t = 0; t <= NT - 3; ++t) {
    char* cb = lds + ((t & 1) << 16);
    char* nb = lds + (((t + 1) & 1) << 16);
    const size_t k1n = (size_t)(t + 1) * 128;
    const size_t k2n = (size_t)(t + 2) * 128;
    // epoch A (E=2t): MFMA P=(t,k0); prefetch Q<-(t,k1); stage (t+1,k1)
    STAGE(Xp, k1n + 64, ABLK(nb, 1));
    STAGE(Wp, k1n + 64, BBLK(nb, 1));
    READ_A(qa, ABLK(cb, 1));
    READ_B(qb, BBLK(cb, 1));
    PIN();
    MFMA32(pa, pb);
    WAIT4;      // confirms stage issued at E-1: (t+1,k0)
    BARRIER();
    // epoch B (E=2t+1): MFMA Q=(t,k1); prefetch P<-(t+1,k0); stage (t+2,k0)
    STAGE(Xp, k2n, ABLK(cb, 0));
    STAGE(Wp, k2n, BBLK(cb, 0));
    READ_A(pa, ABLK(nb, 0));
    READ_B(pb, BBLK(nb, 0));
    PIN();
    MFMA32(qa, qb);
    WAIT4;      // confirms stage issued at E-1: (t+1,k1)
    BARRIER();
  }

  // ---- tail: tile NT-2 ----
  {
    const int t = NT - 2;
    char* cb = lds + ((t & 1) << 16);
    char* nb = lds + (((t + 1) & 1) << 16);
    const size_t k1n = (size_t)(t + 1) * 128;
    // epoch 2NT-4: MFMA (NT-2,k0); prefetch (NT-2,k1); stage (NT-1,k1)
    STAGE(Xp, k1n + 64, ABLK(nb, 1));
    STAGE(Wp, k1n + 64, BBLK(nb, 1));
    READ_A(qa, ABLK(cb, 1));
    READ_B(qb, BBLK(cb, 1));
    PIN();
    MFMA32(pa, pb);
    WAIT4;      // confirms (NT-1,k0)
    BARRIER();
    // epoch 2NT-3: MFMA (NT-2,k1); prefetch (NT-1,k0); no stage
    READ_A(pa, ABLK(nb, 0));
    READ_B(pb, BBLK(nb, 0));
    PIN();
    MFMA32(qa, qb);
    WAIT0;      // confirms (NT-1,k1) (staged at epoch 2NT-4)
    BARRIER();
  }
  // ---- tile NT-1 (no staging, no further waits) ----
  {
    const int t = NT - 1;
    char* cb = lds + ((t & 1) << 16);
    // epoch 2NT-2: MFMA (NT-1,k0); prefetch (NT-1,k1)
    READ_A(qa, ABLK(cb, 1));
    READ_B(qb, BBLK(cb, 1));
    PIN();
    MFMA32(pa, pb);
    // epoch 2NT-1: MFMA (NT-1,k1)
    MFMA32(qa, qb);
  }

  // ---- epilogue: y = scale*acc + bias ----
  // C/D layout: col = lane&15, row = (lane>>4)*4 + reg  [m89/m91-verified]
  const float s = scalep[0];
  float bv[4];
#pragma unroll
  for (int ni = 0; ni < 4; ++ni)
    bv[ni] = bias[bn * 256 + wn * 64 + ni * 16 + r16];

#pragma unroll
  for (int mi = 0; mi < 8; ++mi) {
    const int grow0 = bm * 256 + wm * 128 + mi * 16 + g4 * 4;
#pragma unroll
    for (int r = 0; r < 4; ++r) {
      float* yp = Y + (size_t)(grow0 + r) * N + bn * 256 + wn * 64 + r16;
#pragma unroll
      for (int ni = 0; ni < 4; ++ni)
        yp[ni * 16] = s * acc[mi][ni][r] + bv[ni];
    }
  }
}

// ---------------- fallback: fused kernel (if ws too small) ----------------
#define BM 128
#define BN 128
#define BK 64
#define LDKF (BK * 2)

__global__ __launch_bounds__(256, 2) void qlinear_fused_kernel(
    const float* __restrict__ X, const int32_t* __restrict__ W,
    const float* __restrict__ scalep, const float* __restrict__ bias,
    float* __restrict__ Y)
{
  constexpr int N = 16384, K = 4096;
  __shared__ __align__(16) char slds[(BM + BN) * LDKF];
  char* As = slds;
  char* Bs = slds + BM * LDKF;
  const int tid = threadIdx.x, lane = tid & 63, wid = tid >> 6;
  const int wr = wid >> 1, wc = wid & 1;
  const int nwg = gridDim.x, cpx = nwg >> 3, bid = blockIdx.x;
  const int swz = (bid & 7) * cpx + (bid >> 3);
  const int ntn = N / BN, bm = swz / ntn, bn = swz % ntn;
  const int r16 = lane & 15, g4 = lane >> 4;
  f32x4 acc[4][4];
#pragma unroll
  for (int i = 0; i < 4; ++i)
#pragma unroll
    for (int j = 0; j < 4; ++j) acc[i][j] = (f32x4)0.f;
  const float* Abase = X + (size_t)(bm * BM) * K;
  const int32_t* Bbase = W + (size_t)(bn * BN) * K;
  const int stg_col = (tid & 7) * 8;
  for (int kt = 0; kt < K / BK; ++kt) {
    const int kb = kt * BK;
    if (kt) __syncthreads();
#pragma unroll
    for (int i = 0; i < 4; ++i) {
      const int row = i * 32 + (tid >> 3);
      const float* p = Abase + (size_t)row * K + kb + stg_col;
      f32x4 v0 = *(const f32x4*)p;
      f32x4 v1 = *(const f32x4*)(p + 4);
      u32x4 o = {pk2_rne(v0.x, v0.y), pk2_rne(v0.z, v0.w),
                 pk2_rne(v1.x, v1.y), pk2_rne(v1.z, v1.w)};
      int byte = (row * LDKF + stg_col * 2) ^ ((row & 7) << 4);
      *(u32x4*)(As + byte) = o;
    }
#pragma unroll
    for (int i = 0; i < 4; ++i) {
      const int row = i * 32 + (tid >> 3);
      const int32_t* p = Bbase + (size_t)row * K + kb + stg_col;
      i32x4 v0 = *(const i32x4*)p;
      i32x4 v1 = *(const i32x4*)(p + 4);
      u32x4 o = {pk2_trunc((float)v0.x, (float)v0.y),
                 pk2_trunc((float)v0.z, (float)v0.w),
                 pk2_trunc((float)v1.x, (float)v1.y),
                 pk2_trunc((float)v1.z, (float)v1.w)};
      int byte = (row * LDKF + stg_col * 2) ^ ((row & 7) << 4);
      *(u32x4*)(Bs + byte) = o;
    }
    __syncthreads();
#pragma unroll
    for (int kk = 0; kk < 2; ++kk) {
      bf16x8s af[4], bfr[4];
#pragma unroll
      for (int mi = 0; mi < 4; ++mi) {
        const int row = wr * 64 + mi * 16 + r16;
        int byte = (row * LDKF + kk * 64 + g4 * 16) ^ ((row & 7) << 4);
        af[mi] = *(const bf16x8s*)(As + byte);
      }
#pragma unroll
      for (int ni = 0; ni < 4; ++ni) {
        const int row = wc * 64 + ni * 16 + r16;
        int byte = (row * LDKF + kk * 64 + g4 * 16) ^ ((row & 7) << 4);
        bfr[ni] = *(const bf16x8s*)(Bs + byte);
      }
#pragma unroll
      for (int mi = 0; mi < 4; ++mi)
#pragma unroll
        for (int ni = 0; ni < 4; ++ni)
          acc[mi][ni] = __builtin_amdgcn_mfma_f32_16x16x32_bf16(
              af[mi], bfr[ni], acc[mi][ni], 0, 0, 0);
    }
  }
  const float s = scalep[0];
  float bv[4];
#pragma unroll
  for (int ni = 0; ni < 4; ++ni)
    bv[ni] = bias[bn * BN + wc * 64 + ni * 16 + r16];
#pragma unroll
  for (int mi = 0; mi < 4; ++mi) {
    const int grow0 = bm * BM + wr * 64 + mi * 16 + g4 * 4;
#pragma unroll
    for (int r = 0; r < 4; ++r) {
      float* yp = Y + (size_t)(grow0 + r) * N + bn * BN + wc * 64 + r16;
#pragma unroll
      for (int ni = 0; ni < 4; ++ni)
        yp[ni * 16] = s * acc[mi][ni][r] + bv[ni];
    }
  }
}

extern "C" void kernel_launch(void* const* d_in, const int* in_sizes, int n_in,
                              void* d_out, int out_size, void* d_ws, size_t ws_size,
                              hipStream_t stream) {
  const float*   x  = (const float*)d_in[0];
  const int32_t* w  = (const int32_t*)d_in[1];
  const float*   sc = (const float*)d_in[2];
  const float*   bs = (const float*)d_in[3];
  float*         y  = (float*)d_out;

  constexpr size_t M = 8192, N = 16384, K = 4096;
  const size_t xb_elems = M * K;   // 64 MB bf16
  const size_t wb_elems = N * K;   // 128 MB bf16
  const size_t need = (xb_elems + wb_elems) * 2;

  if (ws_size >= need) {
    uint16_t* xb = (uint16_t*)d_ws;
    uint16_t* wb = xb + xb_elems;
    hipFuncSetAttribute((const void*)qlinear_gemm_256_kernel,
                        hipFuncAttributeMaxDynamicSharedMemorySize, 131072);
    conv_x_kernel<<<2048, 256, 0, stream>>>(x, xb, (int)(xb_elems / 8));
    conv_w_kernel<<<2048, 256, 0, stream>>>(w, wb, (int)(wb_elems / 8));
    qlinear_gemm_256_kernel<<<2048, 512, 131072, stream>>>(xb, wb, sc, bs, y);
  } else {
    qlinear_fused_kernel<<<8192, 256, 0, stream>>>(x, w, sc, bs, y);
  }
}

// Round 10
// 1007.353 us; speedup vs baseline: 1.0097x; 1.0097x over previous
//
#include <hip/hip_runtime.h>
#include <hip/hip_bf16.h>
#include <stdint.h>

// QuantizedLinear: Y[M][N] = scale * (X[M][K] @ W[N][K]^T) + bias[N]
// M=8192, K=4096, N=16384. X fp32, W int32 (harness widens int8), out fp32.
// Round 10: register-prefetch pipeline with MANUAL waitcnt. Fragment reads
// are inline-asm ds_read_b128 (opaque to hipcc -> no compiler lgkmcnt);
// each MFMA cluster is preceded by s_waitcnt lgkmcnt(12) (waits only the
// PREVIOUS epoch's 12 reads; the 12 just-issued prefetch reads stay in
// flight under the MFMAs). sched_barrier(0) fences per rule #18.
// Ring/confirm accounting identical to round 9 (verified): stage at epoch
// E confirmed end E+1 (WAIT4), read at E+2; region rewrite >= 1 barrier
// after the consuming epoch's lgkmcnt(12).

typedef __attribute__((ext_vector_type(4))) float f32x4;
typedef __attribute__((ext_vector_type(4))) int i32x4;
typedef __attribute__((ext_vector_type(8))) short bf16x8s;
typedef __attribute__((ext_vector_type(4))) unsigned int u32x4;

__device__ __forceinline__ uint32_t f2bf_rne(float f) {
  uint32_t x = __float_as_uint(f);
  return (x + 0x7FFFu + ((x >> 16) & 1u)) >> 16;
}
__device__ __forceinline__ uint32_t pk2_rne(float lo, float hi) {
  return f2bf_rne(lo) | (f2bf_rne(hi) << 16);
}
__device__ __forceinline__ uint32_t pk2_trunc(float lo, float hi) {
  return (__float_as_uint(lo) >> 16) | (__float_as_uint(hi) & 0xFFFF0000u);
}

#define GLOAD_LDS16(g, l)                                        \
  __builtin_amdgcn_global_load_lds(                              \
      (const __attribute__((address_space(1))) void*)(g),        \
      (__attribute__((address_space(3))) void*)(l), 16, 0, 0)

// ---------------- conversion kernels (NT loads: inputs are read-once) ------
__global__ __launch_bounds__(256) void conv_x_kernel(
    const float* __restrict__ x, uint16_t* __restrict__ out, int n8) {
  const int stride = blockDim.x * gridDim.x;
  for (int i = blockIdx.x * blockDim.x + threadIdx.x; i < n8; i += stride) {
    f32x4 v0 = __builtin_nontemporal_load((const f32x4*)x + i * 2);
    f32x4 v1 = __builtin_nontemporal_load((const f32x4*)x + i * 2 + 1);
    u32x4 o;
    o.x = pk2_rne(v0.x, v0.y);
    o.y = pk2_rne(v0.z, v0.w);
    o.z = pk2_rne(v1.x, v1.y);
    o.w = pk2_rne(v1.z, v1.w);
    ((u32x4*)out)[i] = o;
  }
}

__global__ __launch_bounds__(256) void conv_w_kernel(
    const int32_t* __restrict__ w, uint16_t* __restrict__ out, int n8) {
  const int stride = blockDim.x * gridDim.x;
  for (int i = blockIdx.x * blockDim.x + threadIdx.x; i < n8; i += stride) {
    i32x4 v0 = __builtin_nontemporal_load((const i32x4*)w + i * 2);
    i32x4 v1 = __builtin_nontemporal_load((const i32x4*)w + i * 2 + 1);
    u32x4 o;
    o.x = pk2_trunc((float)v0.x, (float)v0.y);
    o.y = pk2_trunc((float)v0.z, (float)v0.w);
    o.z = pk2_trunc((float)v1.x, (float)v1.y);
    o.w = pk2_trunc((float)v1.z, (float)v1.w);
    ((u32x4*)out)[i] = o;
  }
}

// ---------------- 256x256 GEMM, asm-read register pipeline ----------------
// LDS: buf b at b*65536; A at +0, B at +32768; K-half kk at kk*16384 =
// [256 rows][32 bf16] (64 B rows). Swizzle: chunk ^= (row>>1)&3 (involution),
// staged via pre-swizzled GLOBAL source + linear LDS dest (rule #21).

#define PIN() __builtin_amdgcn_sched_barrier(0)

#define BARRIER()                 \
  PIN();                          \
  __builtin_amdgcn_s_barrier();   \
  PIN()

#define WAIT4  asm volatile("s_waitcnt vmcnt(4)" ::: "memory"); PIN()
#define WAIT0  asm volatile("s_waitcnt vmcnt(0)" ::: "memory"); PIN()
#define WAITL12 asm volatile("s_waitcnt lgkmcnt(12)" ::: "memory"); PIN()
#define WAITL0  asm volatile("s_waitcnt lgkmcnt(0)" ::: "memory"); PIN()

#define STAGE(mat_base, koffb, ldsbase)                                      \
  {                                                                          \
    GLOAD_LDS16((mat_base) + (size_t)srow * RSB + (koffb) + skch,            \
                (ldsbase) + tid * 16);                                       \
    GLOAD_LDS16((mat_base) + (size_t)(srow + 128) * RSB + (koffb) + skch,    \
                (ldsbase) + 8192 + tid * 16);                                \
  }

#define ABLK(buf, kk) ((buf) + (kk) * 16384)
#define BBLK(buf, kk) ((buf) + 32768 + (kk) * 16384)

// inline-asm ds_read_b128 — invisible to the compiler's waitcnt pass
#define DSR(dst, addr, OFF)                                                  \
  asm volatile("ds_read_b128 %0, %1 offset:" OFF : "=v"(dst) : "v"(addr))

// 12 reads: 8 A-frags (row stride 16 rows = 1024 B) + 4 B-frags
#define READ12(da, db, Aaddr, Baddr)                                         \
  {                                                                          \
    uint32_t _aa = (Aaddr), _bb = (Baddr);                                   \
    DSR(da[0], _aa, "0");    DSR(da[1], _aa, "1024");                        \
    DSR(da[2], _aa, "2048"); DSR(da[3], _aa, "3072");                        \
    DSR(da[4], _aa, "4096"); DSR(da[5], _aa, "5120");                        \
    DSR(da[6], _aa, "6144"); DSR(da[7], _aa, "7168");                        \
    DSR(db[0], _bb, "0");    DSR(db[1], _bb, "1024");                        \
    DSR(db[2], _bb, "2048"); DSR(db[3], _bb, "3072");                        \
  }

#define MFMA32(av, bv)                                                       \
  __builtin_amdgcn_s_setprio(1);                                             \
  _Pragma("unroll") for (int j = 0; j < 8; ++j)                              \
    _Pragma("unroll") for (int ni = 0; ni < 4; ++ni)                         \
      acc[j][ni] = __builtin_amdgcn_mfma_f32_16x16x32_bf16(                  \
          av[j], bv[ni], acc[j][ni], 0, 0, 0);                               \
  __builtin_amdgcn_s_setprio(0);

__global__ __launch_bounds__(512, 2) void qlinear_gemm_256_kernel(
    const uint16_t* __restrict__ Xb,  // [M][K] bf16
    const uint16_t* __restrict__ Wb,  // [N][K] bf16
    const float* __restrict__ scalep,
    const float* __restrict__ bias,
    float* __restrict__ Y)
{
  constexpr int N = 16384, K = 4096;
  constexpr int RSB = K * 2;   // panel row stride, bytes
  constexpr int NT = K / 64;   // 64 K-tiles

  extern __shared__ __align__(16) char lds[];  // 131072 B

  const int tid  = threadIdx.x;
  const int lane = tid & 63;
  const int wid  = tid >> 6;   // 0..7
  const int wm   = wid >> 2;   // 0..1  (M-half of block)
  const int wn   = wid & 3;    // 0..3  (N-quarter of block)
  const int r16  = lane & 15;
  const int g4   = lane >> 4;  // logical k-chunk 0..3
  const int chb  = (g4 ^ ((r16 >> 1) & 3)) << 4;  // swizzled chunk byte off

  const int srow = tid >> 2;                              // 0..127
  const int skch = ((tid & 3) ^ ((tid >> 3) & 3)) * 16;   // pre-swizzled src

  // ---- 2D super-tile mapping (round 6): XCD-private 16x16 patches ----
  const int bid = blockIdx.x;
  const int xcd = bid & 7;
  const int l   = bid >> 3;          // 0..255
  const int bm  = (xcd & 1) * 16 + (l >> 4);
  const int bn  = (xcd >> 1) * 16 + (l & 15);

  f32x4 acc[8][4];
#pragma unroll
  for (int i = 0; i < 8; ++i)
#pragma unroll
    for (int j = 0; j < 4; ++j) acc[i][j] = (f32x4)0.f;

  bf16x8s pa[8], qa[8], pb[4], qb[4];

  const char* Xp = (const char*)Xb + (size_t)(bm * 256) * RSB;
  const char* Wp = (const char*)Wb + (size_t)(bn * 256) * RSB;

  // LDS read base offsets (u32 byte addresses within LDS)
  const uint32_t ldsb = (uint32_t)(uintptr_t)(void*)lds;
  const uint32_t aoff = ldsb + (uint32_t)((wm * 128 + r16) * 64 + chb);
  const uint32_t boff = ldsb + (uint32_t)(32768 + (wn * 64 + r16) * 64 + chb);

  // ---- prologue: stage (0,k0),(0,k1),(1,k0); confirm (0,*); read (0,k0) ----
  STAGE(Xp, 0,   ABLK(lds, 0));
  STAGE(Wp, 0,   BBLK(lds, 0));
  STAGE(Xp, 64,  ABLK(lds, 1));
  STAGE(Wp, 64,  BBLK(lds, 1));
  STAGE(Xp, 128, ABLK(lds + 65536, 0));
  STAGE(Wp, 128, BBLK(lds + 65536, 0));
  WAIT4;        // 12 -> 4: confirms (0,k0) and (0,k1)
  BARRIER();
  READ12(pa, pb, aoff, boff);   // (0,k0)

  // ---- main loop: tiles 0 .. NT-3 ----
  for (int t = 0; t <= NT - 3; ++t) {
    const uint32_t cur = (uint32_t)(t & 1) << 16;
    const uint32_t nxt = cur ^ 65536u;
    char* cb = lds + cur;
    char* nb = lds + nxt;
    const size_t k1n = (size_t)(t + 1) * 128;
    const size_t k2n = (size_t)(t + 2) * 128;
    // epoch A: MFMA (t,k0)=P; prefetch Q<-(t,k1); stage (t+1,k1)
    STAGE(Xp, k1n + 64, ABLK(nb, 1));
    STAGE(Wp, k1n + 64, BBLK(nb, 1));
    READ12(qa, qb, aoff + cur + 16384u, boff + cur + 16384u);
    WAITL12;    // waits previous epoch's 12 reads only (P complete)
    MFMA32(pa, pb);
    WAIT4;      // confirms (t+1,k0), staged one epoch ago
    BARRIER();
    // epoch B: MFMA (t,k1)=Q; prefetch P<-(t+1,k0); stage (t+2,k0)
    STAGE(Xp, k2n, ABLK(cb, 0));
    STAGE(Wp, k2n, BBLK(cb, 0));
    READ12(pa, pb, aoff + nxt, boff + nxt);
    WAITL12;
    MFMA32(qa, qb);
    WAIT4;      // confirms (t+1,k1)
    BARRIER();
  }

  // ---- tail: tile NT-2 (even; cb=buf0, nb=buf1) ----
  {
    const uint32_t cur = (uint32_t)((NT - 2) & 1) << 16;
    const uint32_t nxt = cur ^ 65536u;
    char* nb = lds + nxt;
    const size_t k1n = (size_t)(NT - 1) * 128;
    // epoch A: MFMA (NT-2,k0); prefetch (NT-2,k1); stage (NT-1,k1)
    STAGE(Xp, k1n + 64, ABLK(nb, 1));
    STAGE(Wp, k1n + 64, BBLK(nb, 1));
    READ12(qa, qb, aoff + cur + 16384u, boff + cur + 16384u);
    WAITL12;
    MFMA32(pa, pb);
    WAIT4;      // confirms (NT-1,k0)
    BARRIER();
    // epoch B: MFMA (NT-2,k1); prefetch (NT-1,k0); no stage
    READ12(pa, pb, aoff + nxt, boff + nxt);
    WAITL12;
    MFMA32(qa, qb);
    WAIT0;      // confirms (NT-1,k1)
    BARRIER();
    // tile NT-1, epoch A: MFMA (NT-1,k0); prefetch (NT-1,k1)
    READ12(qa, qb, aoff + nxt + 16384u, boff + nxt + 16384u);
    WAITL12;
    MFMA32(pa, pb);
    // tile NT-1, epoch B: MFMA (NT-1,k1)
    WAITL0;
    MFMA32(qa, qb);
  }

  // ---- epilogue: y = scale*acc + bias ----
  // C/D layout: col = lane&15, row = (lane>>4)*4 + reg  [m89/m91-verified]
  const float s = scalep[0];
  float bv[4];
#pragma unroll
  for (int ni = 0; ni < 4; ++ni)
    bv[ni] = bias[bn * 256 + wn * 64 + ni * 16 + r16];

#pragma unroll
  for (int mi = 0; mi < 8; ++mi) {
    const int grow0 = bm * 256 + wm * 128 + mi * 16 + g4 * 4;
#pragma unroll
    for (int r = 0; r < 4; ++r) {
      float* yp = Y + (size_t)(grow0 + r) * N + bn * 256 + wn * 64 + r16;
#pragma unroll
      for (int ni = 0; ni < 4; ++ni)
        yp[ni * 16] = s * acc[mi][ni][r] + bv[ni];
    }
  }
}

// ---------------- fallback: fused kernel (if ws too small) ----------------
#define BM 128
#define BN 128
#define BK 64
#define LDKF (BK * 2)

__global__ __launch_bounds__(256, 2) void qlinear_fused_kernel(
    const float* __restrict__ X, const int32_t* __restrict__ W,
    const float* __restrict__ scalep, const float* __restrict__ bias,
    float* __restrict__ Y)
{
  constexpr int N = 16384, K = 4096;
  __shared__ __align__(16) char slds[(BM + BN) * LDKF];
  char* As = slds;
  char* Bs = slds + BM * LDKF;
  const int tid = threadIdx.x, lane = tid & 63, wid = tid >> 6;
  const int wr = wid >> 1, wc = wid & 1;
  const int nwg = gridDim.x, cpx = nwg >> 3, bid = blockIdx.x;
  const int swz = (bid & 7) * cpx + (bid >> 3);
  const int ntn = N / BN, bm = swz / ntn, bn = swz % ntn;
  const int r16 = lane & 15, g4 = lane >> 4;
  f32x4 acc[4][4];
#pragma unroll
  for (int i = 0; i < 4; ++i)
#pragma unroll
    for (int j = 0; j < 4; ++j) acc[i][j] = (f32x4)0.f;
  const float* Abase = X + (size_t)(bm * BM) * K;
  const int32_t* Bbase = W + (size_t)(bn * BN) * K;
  const int stg_col = (tid & 7) * 8;
  for (int kt = 0; kt < K / BK; ++kt) {
    const int kb = kt * BK;
    if (kt) __syncthreads();
#pragma unroll
    for (int i = 0; i < 4; ++i) {
      const int row = i * 32 + (tid >> 3);
      const float* p = Abase + (size_t)row * K + kb + stg_col;
      f32x4 v0 = *(const f32x4*)p;
      f32x4 v1 = *(const f32x4*)(p + 4);
      u32x4 o = {pk2_rne(v0.x, v0.y), pk2_rne(v0.z, v0.w),
                 pk2_rne(v1.x, v1.y), pk2_rne(v1.z, v1.w)};
      int byte = (row * LDKF + stg_col * 2) ^ ((row & 7) << 4);
      *(u32x4*)(As + byte) = o;
    }
#pragma unroll
    for (int i = 0; i < 4; ++i) {
      const int row = i * 32 + (tid >> 3);
      const int32_t* p = Bbase + (size_t)row * K + kb + stg_col;
      i32x4 v0 = *(const i32x4*)p;
      i32x4 v1 = *(const i32x4*)(p + 4);
      u32x4 o = {pk2_trunc((float)v0.x, (float)v0.y),
                 pk2_trunc((float)v0.z, (float)v0.w),
                 pk2_trunc((float)v1.x, (float)v1.y),
                 pk2_trunc((float)v1.z, (float)v1.w)};
      int byte = (row * LDKF + stg_col * 2) ^ ((row & 7) << 4);
      *(u32x4*)(Bs + byte) = o;
    }
    __syncthreads();
#pragma unroll
    for (int kk = 0; kk < 2; ++kk) {
      bf16x8s af[4], bfr[4];
#pragma unroll
      for (int mi = 0; mi < 4; ++mi) {
        const int row = wr * 64 + mi * 16 + r16;
        int byte = (row * LDKF + kk * 64 + g4 * 16) ^ ((row & 7) << 4);
        af[mi] = *(const bf16x8s*)(As + byte);
      }
#pragma unroll
      for (int ni = 0; ni < 4; ++ni) {
        const int row = wc * 64 + ni * 16 + r16;
        int byte = (row * LDKF + kk * 64 + g4 * 16) ^ ((row & 7) << 4);
        bfr[ni] = *(const bf16x8s*)(Bs + byte);
      }
#pragma unroll
      for (int mi = 0; mi < 4; ++mi)
#pragma unroll
        for (int ni = 0; ni < 4; ++ni)
          acc[mi][ni] = __builtin_amdgcn_mfma_f32_16x16x32_bf16(
              af[mi], bfr[ni], acc[mi][ni], 0, 0, 0);
    }
  }
  const float s = scalep[0];
  float bv[4];
#pragma unroll
  for (int ni = 0; ni < 4; ++ni)
    bv[ni] = bias[bn * BN + wc * 64 + ni * 16 + r16];
#pragma unroll
  for (int mi = 0; mi < 4; ++mi) {
    const int grow0 = bm * BM + wr * 64 + mi * 16 + g4 * 4;
#pragma unroll
    for (int r = 0; r < 4; ++r) {
      float* yp = Y + (size_t)(grow0 + r) * N + bn * BN + wc * 64 + r16;
#pragma unroll
      for (int ni = 0; ni < 4; ++ni)
        yp[ni * 16] = s * acc[mi][ni][r] + bv[ni];
    }
  }
}

extern "C" void kernel_launch(void* const* d_in, const int* in_sizes, int n_in,
                              void* d_out, int out_size, void* d_ws, size_t ws_size,
                              hipStream_t stream) {
  const float*   x  = (const float*)d_in[0];
  const int32_t* w  = (const int32_t*)d_in[1];
  const float*   sc = (const float*)d_in[2];
  const float*   bs = (const float*)d_in[3];
  float*         y  = (float*)d_out;

  constexpr size_t M = 8192, N = 16384, K = 4096;
  const size_t xb_elems = M * K;   // 64 MB bf16
  const size_t wb_elems = N * K;   // 128 MB bf16
  const size_t need = (xb_elems + wb_elems) * 2;

  if (ws_size >= need) {
    uint16_t* xb = (uint16_t*)d_ws;
    uint16_t* wb = xb + xb_elems;
    hipFuncSetAttribute((const void*)qlinear_gemm_256_kernel,
                        hipFuncAttributeMaxDynamicSharedMemorySize, 131072);
    conv_x_kernel<<<2048, 256, 0, stream>>>(x, xb, (int)(xb_elems / 8));
    conv_w_kernel<<<2048, 256, 0, stream>>>(w, wb, (int)(wb_elems / 8));
    qlinear_gemm_256_kernel<<<2048, 512, 131072, stream>>>(xb, wb, sc, bs, y);
  } else {
    qlinear_fused_kernel<<<8192, 256, 0, stream>>>(x, w, sc, bs, y);
  }
}

// Round 11
// 975.732 us; speedup vs baseline: 1.0424x; 1.0324x over previous
//
#include <hip/hip_runtime.h>
#include <hip/hip_bf16.h>
#include <stdint.h>

// QuantizedLinear: Y[M][N] = scale * (X[M][K] @ W[N][K]^T) + bias[N]
// M=8192, K=4096, N=16384. X fp32, W int32 (harness widens int8), out fp32.
// Round 11: fine-grained DS_READ||MFMA interleave. Each epoch emits
// {2 ds_read, 4 MFMA} x6 + {4 MFMA} x2 with sched_barrier(0) pins, so the
// DS pipe drains next-epoch fragment reads UNDER the matrix pipe instead
// of backing up the in-order issue queue ahead of the MFMAs (r8-r10 all
// measured epoch = LDS + MFMA sum; cause was issue backpressure from
// batched reads). Single lgkmcnt(0) at epoch start (prev reads complete
// => ~free) doubles as the read-before-restage anchor. Ring/vmcnt
// accounting identical to round 10 (verified, passed).

typedef __attribute__((ext_vector_type(4))) float f32x4;
typedef __attribute__((ext_vector_type(4))) int i32x4;
typedef __attribute__((ext_vector_type(8))) short bf16x8s;
typedef __attribute__((ext_vector_type(4))) unsigned int u32x4;

__device__ __forceinline__ uint32_t f2bf_rne(float f) {
  uint32_t x = __float_as_uint(f);
  return (x + 0x7FFFu + ((x >> 16) & 1u)) >> 16;
}
__device__ __forceinline__ uint32_t pk2_rne(float lo, float hi) {
  return f2bf_rne(lo) | (f2bf_rne(hi) << 16);
}
__device__ __forceinline__ uint32_t pk2_trunc(float lo, float hi) {
  return (__float_as_uint(lo) >> 16) | (__float_as_uint(hi) & 0xFFFF0000u);
}

#define GLOAD_LDS16(g, l)                                        \
  __builtin_amdgcn_global_load_lds(                              \
      (const __attribute__((address_space(1))) void*)(g),        \
      (__attribute__((address_space(3))) void*)(l), 16, 0, 0)

// ---------------- conversion kernels (NT loads: inputs are read-once) ------
__global__ __launch_bounds__(256) void conv_x_kernel(
    const float* __restrict__ x, uint16_t* __restrict__ out, int n8) {
  const int stride = blockDim.x * gridDim.x;
  for (int i = blockIdx.x * blockDim.x + threadIdx.x; i < n8; i += stride) {
    f32x4 v0 = __builtin_nontemporal_load((const f32x4*)x + i * 2);
    f32x4 v1 = __builtin_nontemporal_load((const f32x4*)x + i * 2 + 1);
    u32x4 o;
    o.x = pk2_rne(v0.x, v0.y);
    o.y = pk2_rne(v0.z, v0.w);
    o.z = pk2_rne(v1.x, v1.y);
    o.w = pk2_rne(v1.z, v1.w);
    ((u32x4*)out)[i] = o;
  }
}

__global__ __launch_bounds__(256) void conv_w_kernel(
    const int32_t* __restrict__ w, uint16_t* __restrict__ out, int n8) {
  const int stride = blockDim.x * gridDim.x;
  for (int i = blockIdx.x * blockDim.x + threadIdx.x; i < n8; i += stride) {
    i32x4 v0 = __builtin_nontemporal_load((const i32x4*)w + i * 2);
    i32x4 v1 = __builtin_nontemporal_load((const i32x4*)w + i * 2 + 1);
    u32x4 o;
    o.x = pk2_trunc((float)v0.x, (float)v0.y);
    o.y = pk2_trunc((float)v0.z, (float)v0.w);
    o.z = pk2_trunc((float)v1.x, (float)v1.y);
    o.w = pk2_trunc((float)v1.z, (float)v1.w);
    ((u32x4*)out)[i] = o;
  }
}

// ---------------- 256x256 GEMM, interleaved asm-read pipeline -------------
// LDS: buf b at b*65536; A at +0, B at +32768; K-half kk at kk*16384 =
// [256 rows][32 bf16] (64 B rows). Swizzle: chunk ^= (row>>1)&3 (involution),
// staged via pre-swizzled GLOBAL source + linear LDS dest (rule #21).

#define PIN() __builtin_amdgcn_sched_barrier(0)

#define BARRIER()                 \
  PIN();                          \
  __builtin_amdgcn_s_barrier();   \
  PIN()

#define WAIT4  asm volatile("s_waitcnt vmcnt(4)" ::: "memory"); PIN()
#define WAIT0  asm volatile("s_waitcnt vmcnt(0)" ::: "memory"); PIN()
#define WAITL0 asm volatile("s_waitcnt lgkmcnt(0)" ::: "memory"); PIN()

#define STAGE(mat_base, koffb, ldsbase)                                      \
  {                                                                          \
    GLOAD_LDS16((mat_base) + (size_t)srow * RSB + (koffb) + skch,            \
                (ldsbase) + tid * 16);                                       \
    GLOAD_LDS16((mat_base) + (size_t)(srow + 128) * RSB + (koffb) + skch,    \
                (ldsbase) + 8192 + tid * 16);                                \
  }

#define ABLK(buf, kk) ((buf) + (kk) * 16384)
#define BBLK(buf, kk) ((buf) + 32768 + (kk) * 16384)

// inline-asm ds_read_b128 — invisible to the compiler's waitcnt pass
#define DSR(dst, addr, OFF)                                                  \
  asm volatile("ds_read_b128 %0, %1 offset:" OFF : "=v"(dst) : "v"(addr))

// prologue-only: 12 batched reads (first fill)
#define READ12(da, db, Aaddr, Baddr)                                         \
  {                                                                          \
    uint32_t _aa = (Aaddr), _bb = (Baddr);                                   \
    DSR(da[0], _aa, "0");    DSR(da[1], _aa, "1024");                        \
    DSR(da[2], _aa, "2048"); DSR(da[3], _aa, "3072");                        \
    DSR(da[4], _aa, "4096"); DSR(da[5], _aa, "5120");                        \
    DSR(da[6], _aa, "6144"); DSR(da[7], _aa, "7168");                        \
    DSR(db[0], _bb, "0");    DSR(db[1], _bb, "1024");                        \
    DSR(db[2], _bb, "2048"); DSR(db[3], _bb, "3072");                        \
  }

#define MFMA4(av, bv, j)                                                     \
  _Pragma("unroll") for (int ni = 0; ni < 4; ++ni)                           \
    acc[j][ni] = __builtin_amdgcn_mfma_f32_16x16x32_bf16(                    \
        av[j], bv[ni], acc[j][ni], 0, 0, 0);

// One epoch's compute: 32 MFMAs on (av,bv) interleaved with the 12
// ds_reads that fill (xa,xb) for the NEXT epoch. Pins force the interleave.
#define EPOCH_ILV(av, bv, xa, xb, Aaddr, Baddr)                              \
  {                                                                          \
    uint32_t _aa = (Aaddr), _bb = (Baddr);                                   \
    __builtin_amdgcn_s_setprio(1);                                           \
    DSR(xa[0], _aa, "0");    DSR(xa[1], _aa, "1024");   PIN();               \
    MFMA4(av, bv, 0);                                   PIN();               \
    DSR(xa[2], _aa, "2048"); DSR(xa[3], _aa, "3072");   PIN();               \
    MFMA4(av, bv, 1);                                   PIN();               \
    DSR(xa[4], _aa, "4096"); DSR(xa[5], _aa, "5120");   PIN();               \
    MFMA4(av, bv, 2);                                   PIN();               \
    DSR(xa[6], _aa, "6144"); DSR(xa[7], _aa, "7168");   PIN();               \
    MFMA4(av, bv, 3);                                   PIN();               \
    DSR(xb[0], _bb, "0");    DSR(xb[1], _bb, "1024");   PIN();               \
    MFMA4(av, bv, 4);                                   PIN();               \
    DSR(xb[2], _bb, "2048"); DSR(xb[3], _bb, "3072");   PIN();               \
    MFMA4(av, bv, 5);                                   PIN();               \
    MFMA4(av, bv, 6);                                                        \
    MFMA4(av, bv, 7);                                                        \
    __builtin_amdgcn_s_setprio(0);                                           \
  }

// last epoch: plain 32 MFMAs, no prefetch
#define MFMA32(av, bv)                                                       \
  __builtin_amdgcn_s_setprio(1);                                             \
  _Pragma("unroll") for (int j = 0; j < 8; ++j)                              \
    _Pragma("unroll") for (int ni = 0; ni < 4; ++ni)                         \
      acc[j][ni] = __builtin_amdgcn_mfma_f32_16x16x32_bf16(                  \
          av[j], bv[ni], acc[j][ni], 0, 0, 0);                               \
  __builtin_amdgcn_s_setprio(0);

__global__ __launch_bounds__(512, 2) void qlinear_gemm_256_kernel(
    const uint16_t* __restrict__ Xb,  // [M][K] bf16
    const uint16_t* __restrict__ Wb,  // [N][K] bf16
    const float* __restrict__ scalep,
    const float* __restrict__ bias,
    float* __restrict__ Y)
{
  constexpr int N = 16384, K = 4096;
  constexpr int RSB = K * 2;   // panel row stride, bytes
  constexpr int NT = K / 64;   // 64 K-tiles

  extern __shared__ __align__(16) char lds[];  // 131072 B

  const int tid  = threadIdx.x;
  const int lane = tid & 63;
  const int wid  = tid >> 6;   // 0..7
  const int wm   = wid >> 2;   // 0..1  (M-half of block)
  const int wn   = wid & 3;    // 0..3  (N-quarter of block)
  const int r16  = lane & 15;
  const int g4   = lane >> 4;  // logical k-chunk 0..3
  const int chb  = (g4 ^ ((r16 >> 1) & 3)) << 4;  // swizzled chunk byte off

  const int srow = tid >> 2;                              // 0..127
  const int skch = ((tid & 3) ^ ((tid >> 3) & 3)) * 16;   // pre-swizzled src

  // ---- 2D super-tile mapping (round 6): XCD-private 16x16 patches ----
  const int bid = blockIdx.x;
  const int xcd = bid & 7;
  const int l   = bid >> 3;          // 0..255
  const int bm  = (xcd & 1) * 16 + (l >> 4);
  const int bn  = (xcd >> 1) * 16 + (l & 15);

  f32x4 acc[8][4];
#pragma unroll
  for (int i = 0; i < 8; ++i)
#pragma unroll
    for (int j = 0; j < 4; ++j) acc[i][j] = (f32x4)0.f;

  bf16x8s pa[8], qa[8], pb[4], qb[4];

  const char* Xp = (const char*)Xb + (size_t)(bm * 256) * RSB;
  const char* Wp = (const char*)Wb + (size_t)(bn * 256) * RSB;

  // LDS read base offsets (u32 byte addresses within LDS)
  const uint32_t ldsb = (uint32_t)(uintptr_t)(void*)lds;
  const uint32_t aoff = ldsb + (uint32_t)((wm * 128 + r16) * 64 + chb);
  const uint32_t boff = ldsb + (uint32_t)(32768 + (wn * 64 + r16) * 64 + chb);

  // ---- prologue: stage (0,k0),(0,k1),(1,k0); confirm (0,*); read (0,k0) ----
  STAGE(Xp, 0,   ABLK(lds, 0));
  STAGE(Wp, 0,   BBLK(lds, 0));
  STAGE(Xp, 64,  ABLK(lds, 1));
  STAGE(Wp, 64,  BBLK(lds, 1));
  STAGE(Xp, 128, ABLK(lds + 65536, 0));
  STAGE(Wp, 128, BBLK(lds + 65536, 0));
  WAIT4;        // 12 -> 4: confirms (0,k0) and (0,k1)
  BARRIER();
  READ12(pa, pb, aoff, boff);   // (0,k0); loop's first WAITL0 drains these

  // ---- main loop: tiles 0 .. NT-3 ----
  for (int t = 0; t <= NT - 3; ++t) {
    const uint32_t cur = (uint32_t)(t & 1) << 16;
    const uint32_t nxt = cur ^ 65536u;
    char* cb = lds + cur;
    char* nb = lds + nxt;
    const size_t k1n = (size_t)(t + 1) * 128;
    const size_t k2n = (size_t)(t + 2) * 128;
    // epoch A: MFMA (t,k0)=P; interleave-prefetch Q<-(t,k1); stage (t+1,k1)
    STAGE(Xp, k1n + 64, ABLK(nb, 1));
    STAGE(Wp, k1n + 64, BBLK(nb, 1));
    WAITL0;     // P frags landed (issued interleaved during prev epoch)
    EPOCH_ILV(pa, pb, qa, qb, aoff + cur + 16384u, boff + cur + 16384u);
    WAIT4;      // confirms (t+1,k0), staged one epoch ago
    BARRIER();
    // epoch B: MFMA (t,k1)=Q; interleave-prefetch P<-(t+1,k0); stage (t+2,k0)
    STAGE(Xp, k2n, ABLK(cb, 0));
    STAGE(Wp, k2n, BBLK(cb, 0));
    WAITL0;
    EPOCH_ILV(qa, qb, pa, pb, aoff + nxt, boff + nxt);
    WAIT4;      // confirms (t+1,k1)
    BARRIER();
  }

  // ---- tail: tile NT-2 (even; cur=buf0, nxt=buf1) ----
  {
    const uint32_t cur = (uint32_t)((NT - 2) & 1) << 16;
    const uint32_t nxt = cur ^ 65536u;
    char* nb = lds + nxt;
    const size_t k1n = (size_t)(NT - 1) * 128;
    // epoch A: MFMA (NT-2,k0); prefetch (NT-2,k1); stage (NT-1,k1)
    STAGE(Xp, k1n + 64, ABLK(nb, 1));
    STAGE(Wp, k1n + 64, BBLK(nb, 1));
    WAITL0;
    EPOCH_ILV(pa, pb, qa, qb, aoff + cur + 16384u, boff + cur + 16384u);
    WAIT4;      // confirms (NT-1,k0)
    BARRIER();
    // epoch B: MFMA (NT-2,k1); prefetch (NT-1,k0); no stage
    WAITL0;
    EPOCH_ILV(qa, qb, pa, pb, aoff + nxt, boff + nxt);
    WAIT0;      // confirms (NT-1,k1)
    BARRIER();
    // tile NT-1, epoch A: MFMA (NT-1,k0); prefetch (NT-1,k1)
    WAITL0;
    EPOCH_ILV(pa, pb, qa, qb, aoff + nxt + 16384u, boff + nxt + 16384u);
    // tile NT-1, epoch B: MFMA (NT-1,k1)
    WAITL0;
    MFMA32(qa, qb);
  }

  // ---- epilogue: y = scale*acc + bias ----
  // C/D layout: col = lane&15, row = (lane>>4)*4 + reg  [m89/m91-verified]
  const float s = scalep[0];
  float bv[4];
#pragma unroll
  for (int ni = 0; ni < 4; ++ni)
    bv[ni] = bias[bn * 256 + wn * 64 + ni * 16 + r16];

#pragma unroll
  for (int mi = 0; mi < 8; ++mi) {
    const int grow0 = bm * 256 + wm * 128 + mi * 16 + g4 * 4;
#pragma unroll
    for (int r = 0; r < 4; ++r) {
      float* yp = Y + (size_t)(grow0 + r) * N + bn * 256 + wn * 64 + r16;
#pragma unroll
      for (int ni = 0; ni < 4; ++ni)
        yp[ni * 16] = s * acc[mi][ni][r] + bv[ni];
    }
  }
}

// ---------------- fallback: fused kernel (if ws too small) ----------------
#define BM 128
#define BN 128
#define BK 64
#define LDKF (BK * 2)

__global__ __launch_bounds__(256, 2) void qlinear_fused_kernel(
    const float* __restrict__ X, const int32_t* __restrict__ W,
    const float* __restrict__ scalep, const float* __restrict__ bias,
    float* __restrict__ Y)
{
  constexpr int N = 16384, K = 4096;
  __shared__ __align__(16) char slds[(BM + BN) * LDKF];
  char* As = slds;
  char* Bs = slds + BM * LDKF;
  const int tid = threadIdx.x, lane = tid & 63, wid = tid >> 6;
  const int wr = wid >> 1, wc = wid & 1;
  const int nwg = gridDim.x, cpx = nwg >> 3, bid = blockIdx.x;
  const int swz = (bid & 7) * cpx + (bid >> 3);
  const int ntn = N / BN, bm = swz / ntn, bn = swz % ntn;
  const int r16 = lane & 15, g4 = lane >> 4;
  f32x4 acc[4][4];
#pragma unroll
  for (int i = 0; i < 4; ++i)
#pragma unroll
    for (int j = 0; j < 4; ++j) acc[i][j] = (f32x4)0.f;
  const float* Abase = X + (size_t)(bm * BM) * K;
  const int32_t* Bbase = W + (size_t)(bn * BN) * K;
  const int stg_col = (tid & 7) * 8;
  for (int kt = 0; kt < K / BK; ++kt) {
    const int kb = kt * BK;
    if (kt) __syncthreads();
#pragma unroll
    for (int i = 0; i < 4; ++i) {
      const int row = i * 32 + (tid >> 3);
      const float* p = Abase + (size_t)row * K + kb + stg_col;
      f32x4 v0 = *(const f32x4*)p;
      f32x4 v1 = *(const f32x4*)(p + 4);
      u32x4 o = {pk2_rne(v0.x, v0.y), pk2_rne(v0.z, v0.w),
                 pk2_rne(v1.x, v1.y), pk2_rne(v1.z, v1.w)};
      int byte = (row * LDKF + stg_col * 2) ^ ((row & 7) << 4);
      *(u32x4*)(As + byte) = o;
    }
#pragma unroll
    for (int i = 0; i < 4; ++i) {
      const int row = i * 32 + (tid >> 3);
      const int32_t* p = Bbase + (size_t)row * K + kb + stg_col;
      i32x4 v0 = *(const i32x4*)p;
      i32x4 v1 = *(const i32x4*)(p + 4);
      u32x4 o = {pk2_trunc((float)v0.x, (float)v0.y),
                 pk2_trunc((float)v0.z, (float)v0.w),
                 pk2_trunc((float)v1.x, (float)v1.y),
                 pk2_trunc((float)v1.z, (float)v1.w)};
      int byte = (row * LDKF + stg_col * 2) ^ ((row & 7) << 4);
      *(u32x4*)(Bs + byte) = o;
    }
    __syncthreads();
#pragma unroll
    for (int kk = 0; kk < 2; ++kk) {
      bf16x8s af[4], bfr[4];
#pragma unroll
      for (int mi = 0; mi < 4; ++mi) {
        const int row = wr * 64 + mi * 16 + r16;
        int byte = (row * LDKF + kk * 64 + g4 * 16) ^ ((row & 7) << 4);
        af[mi] = *(const bf16x8s*)(As + byte);
      }
#pragma unroll
      for (int ni = 0; ni < 4; ++ni) {
        const int row = wc * 64 + ni * 16 + r16;
        int byte = (row * LDKF + kk * 64 + g4 * 16) ^ ((row & 7) << 4);
        bfr[ni] = *(const bf16x8s*)(Bs + byte);
      }
#pragma unroll
      for (int mi = 0; mi < 4; ++mi)
#pragma unroll
        for (int ni = 0; ni < 4; ++ni)
          acc[mi][ni] = __builtin_amdgcn_mfma_f32_16x16x32_bf16(
              af[mi], bfr[ni], acc[mi][ni], 0, 0, 0);
    }
  }
  const float s = scalep[0];
  float bv[4];
#pragma unroll
  for (int ni = 0; ni < 4; ++ni)
    bv[ni] = bias[bn * BN + wc * 64 + ni * 16 + r16];
#pragma unroll
  for (int mi = 0; mi < 4; ++mi) {
    const int grow0 = bm * BM + wr * 64 + mi * 16 + g4 * 4;
#pragma unroll
    for (int r = 0; r < 4; ++r) {
      float* yp = Y + (size_t)(grow0 + r) * N + bn * BN + wc * 64 + r16;
#pragma unroll
      for (int ni = 0; ni < 4; ++ni)
        yp[ni * 16] = s * acc[mi][ni][r] + bv[ni];
    }
  }
}

extern "C" void kernel_launch(void* const* d_in, const int* in_sizes, int n_in,
                              void* d_out, int out_size, void* d_ws, size_t ws_size,
                              hipStream_t stream) {
  const float*   x  = (const float*)d_in[0];
  const int32_t* w  = (const int32_t*)d_in[1];
  const float*   sc = (const float*)d_in[2];
  const float*   bs = (const float*)d_in[3];
  float*         y  = (float*)d_out;

  constexpr size_t M = 8192, N = 16384, K = 4096;
  const size_t xb_elems = M * K;   // 64 MB bf16
  const size_t wb_elems = N * K;   // 128 MB bf16
  const size_t need = (xb_elems + wb_elems) * 2;

  if (ws_size >= need) {
    uint16_t* xb = (uint16_t*)d_ws;
    uint16_t* wb = xb + xb_elems;
    hipFuncSetAttribute((const void*)qlinear_gemm_256_kernel,
                        hipFuncAttributeMaxDynamicSharedMemorySize, 131072);
    conv_x_kernel<<<2048, 256, 0, stream>>>(x, xb, (int)(xb_elems / 8));
    conv_w_kernel<<<2048, 256, 0, stream>>>(w, wb, (int)(wb_elems / 8));
    qlinear_gemm_256_kernel<<<2048, 512, 131072, stream>>>(xb, wb, sc, bs, y);
  } else {
    qlinear_fused_kernel<<<8192, 256, 0, stream>>>(x, w, sc, bs, y);
  }
}